// Round 5
// baseline (911.946 us; speedup 1.0000x reference)
//
#include <hip/hip_runtime.h>

// Problem constants (fixed by setup_inputs)
#define BB 4
#define Q 75
#define WAY 5
#define HW 100
#define D 640
#define M 500          // shot*HW
#define QROWS 7500     // Q*HW
#define NDQ 30000      // BB*QROWS query descriptors

// ws layout: floats at low offsets, pre-split B arrays at byte offsets.
// TOTAL ws ask: ~27.3 MB (known-good from R4).
#define WS_QINV 0
#define WS_SINV 30000
#define WS_QMEAN 40000     // BB*Q*D = 192000
#define WS_PROTO 232000    // BB*WAY*D = 12800
#define WS_FEAT 244800     // BB*Q*10 = 3000
#define WS_BH_BYTE 1048576u               // 20*32*20*1024 = 13107200 B
#define WS_BL_BYTE (1048576u + 13107200u)

using short8  = __attribute__((ext_vector_type(8))) short;
using short4v = __attribute__((ext_vector_type(4))) short;
using float4v = __attribute__((ext_vector_type(4))) float;

__device__ __forceinline__ void split1(float v, unsigned short& h, unsigned short& l) {
    unsigned u = __float_as_uint(v);
    unsigned short hu = (unsigned short)(u >> 16);          // truncate to bf16
    float hf = __uint_as_float(u & 0xffff0000u);
    float lo = v - hf;                                       // exact residual
    unsigned short lu = (unsigned short)(__float_as_uint(lo) >> 16);
    h = hu; l = lu;
}

__device__ __forceinline__ void split_store(float4 v, float s, short* dh, short* dl) {
    unsigned short h0,h1,h2,h3,l0,l1,l2,l3;
    split1(v.x * s, h0, l0); split1(v.y * s, h1, l1);
    split1(v.z * s, h2, l2); split1(v.w * s, h3, l3);
    short4v hv, lv;
    hv[0]=(short)h0; hv[1]=(short)h1; hv[2]=(short)h2; hv[3]=(short)h3;
    lv[0]=(short)l0; lv[1]=(short)l1; lv[2]=(short)l2; lv[3]=(short)l3;
    *(short4v*)dh = hv;
    *(short4v*)dl = lv;
}

// in-register split of 8 elements (scaled) into bf16 hi/lo fragments
__device__ __forceinline__ void split8(float4 a0, float4 a1, float s, short8& h8, short8& l8) {
    float e0 = a0.x, e1 = a0.y, e2 = a0.z, e3 = a0.w;
    float e4 = a1.x, e5 = a1.y, e6 = a1.z, e7 = a1.w;
    unsigned short h, l;
    split1(e0 * s, h, l); h8[0] = (short)h; l8[0] = (short)l;
    split1(e1 * s, h, l); h8[1] = (short)h; l8[1] = (short)l;
    split1(e2 * s, h, l); h8[2] = (short)h; l8[2] = (short)l;
    split1(e3 * s, h, l); h8[3] = (short)h; l8[3] = (short)l;
    split1(e4 * s, h, l); h8[4] = (short)h; l8[4] = (short)l;
    split1(e5 * s, h, l); h8[5] = (short)h; l8[5] = (short)l;
    split1(e6 * s, h, l); h8[6] = (short)h; l8[6] = (short)l;
    split1(e7 * s, h, l); h8[7] = (short)h; l8[7] = (short)l;
}

// ---------------- kernel 0: pre-split B (normalize + bf16 hi/lo, frag-order) ---
// block = (bw, rf): 16 support rows x 640 k. Output frag layout:
// byte = ((bw*32+rf)*20 + kt)*1024 + lane*16, lane = lq*16+rho holds
// B[n=rf*16+rho][k=kt*32+lq*8+j], j=0..7.
__global__ __launch_bounds__(256) void presplit_b(const float* __restrict__ xs,
                                                  float* __restrict__ ws) {
    __shared__ float partial[256];
    __shared__ float sinvS[16];
    __shared__ short Sh[16][648];
    __shared__ short Sl[16][648];
    int bw = blockIdx.x >> 5;      // 0..19
    int rf = blockIdx.x & 31;      // 0..31
    int tid = threadIdx.x;
    int rho = tid & 15;
    int kc  = tid >> 4;            // 0..15, covers k in [kc*40, kc*40+40)
    int m = rf * 16 + rho;
    bool valid = (m < M);
    const float* src = xs + ((size_t)bw * M + m) * D + kc * 40;

    float4 v[10];
    float ss = 0.f;
    #pragma unroll
    for (int i = 0; i < 10; ++i) {
        v[i] = valid ? *(const float4*)(src + i * 4) : make_float4(0.f,0.f,0.f,0.f);
        ss += v[i].x*v[i].x + v[i].y*v[i].y + v[i].z*v[i].z + v[i].w*v[i].w;
    }
    partial[tid] = ss;
    __syncthreads();
    if (tid < 16) {
        float sum = 0.f;
        #pragma unroll
        for (int k = 0; k < 16; ++k) sum += partial[k * 16 + tid];
        float inv = (sum > 0.f) ? rsqrtf(sum) : 0.f;
        sinvS[tid] = inv;
        int mm = rf * 16 + tid;
        if (mm < M) ws[WS_SINV + bw * M + mm] = inv;
    }
    __syncthreads();
    float s = sinvS[rho];
    #pragma unroll
    for (int i = 0; i < 10; ++i) {
        int k = kc * 40 + i * 4;
        split_store(v[i], s, &Sh[rho][k], &Sl[rho][k]);
    }
    __syncthreads();
    // output: wave wv handles kt = wv*5 + p
    int lane = tid & 63, wv = tid >> 6;
    int rs = lane & 15, kg = lane >> 4;
    char* wsb = (char*)ws;
    #pragma unroll
    for (int p = 0; p < 5; ++p) {
        int kt = wv * 5 + p;
        short8 hv = *(const short8*)&Sh[rs][kt * 32 + kg * 8];
        short8 lv = *(const short8*)&Sl[rs][kt * 32 + kg * 8];
        size_t fo = ((size_t)(bw * 32 + rf) * 20 + kt) * 1024 + lane * 16;
        *(short8*)(wsb + WS_BH_BYTE + fo) = hv;
        *(short8*)(wsb + WS_BL_BYTE + fo) = lv;
    }
}

// ---------------- kernel 1: inverse L2 norms of query descriptors --------------
__global__ void norms_kernel(const float* __restrict__ xq, float* __restrict__ ws) {
    int wid  = (int)((blockIdx.x * blockDim.x + threadIdx.x) >> 6);
    int lane = threadIdx.x & 63;
    if (wid >= NDQ) return;
    const float* p = xq + (size_t)wid * D;
    float s = 0.f;
    #pragma unroll
    for (int j = 0; j < D; j += 64) { float v = p[j + lane]; s += v * v; }
    for (int off = 32; off; off >>= 1) s += __shfl_down(s, off);
    if (lane == 0) ws[WS_QINV + wid] = rsqrtf(s);
}

// ---------------- kernel 2: query_mean (over HW) and proto (over shot*HW) ------
__global__ void means_kernel(const float* __restrict__ xq, const float* __restrict__ xs,
                             float* __restrict__ ws) {
    __shared__ float inv[M];
    int bid = blockIdx.x;
    if (bid < BB * Q) {
        for (int i = threadIdx.x; i < HW; i += blockDim.x) inv[i] = ws[WS_QINV + bid * HW + i];
        __syncthreads();
        const float* base = xq + (size_t)bid * HW * D;
        for (int d = threadIdx.x; d < D; d += blockDim.x) {
            float s = 0.f;
            for (int h = 0; h < HW; ++h) s += base[(size_t)h * D + d] * inv[h];
            ws[WS_QMEAN + bid * D + d] = s * (1.f / HW);
        }
    } else {
        int bw = bid - BB * Q; // 0..19
        for (int i = threadIdx.x; i < M; i += blockDim.x) inv[i] = ws[WS_SINV + bw * M + i];
        __syncthreads();
        const float* base = xs + (size_t)bw * M * D;
        for (int d = threadIdx.x; d < D; d += blockDim.x) {
            float s = 0.f;
            for (int m = 0; m < M; ++m) s += base[(size_t)m * D + d] * inv[m];
            ws[WS_PROTO + bw * D + d] = s * (1.f / M);
        }
    }
}

// ---------------- kernel 3: cosine-prototype logits + zero-init sim slots ------
__global__ void cos_kernel(float* __restrict__ ws) {
    int idx  = (int)((blockIdx.x * blockDim.x + threadIdx.x) >> 6);
    int lane = threadIdx.x & 63;
    if (idx >= BB * Q * WAY) return;
    int w = idx % WAY; int bq = idx / WAY; int b = bq / Q;
    const float* qm = ws + WS_QMEAN + bq * D;
    const float* pr = ws + WS_PROTO + (b * WAY + w) * D;
    float s = 0.f;
    #pragma unroll
    for (int j = 0; j < D; j += 64) s += qm[j + lane] * pr[j + lane];
    for (int off = 32; off; off >>= 1) s += __shfl_down(s, off);
    if (lane == 0) {
        ws[WS_FEAT + bq * 10 + w]     = s;
        ws[WS_FEAT + bq * 10 + 5 + w] = 0.f;
    }
}

// ---------------- kernel 4: barrier-free MFMA split-bf16 GEMM + top-5 ----------
// Block: 128 rows x full M (4 chunks of 128 cols, processed as 2 pairs).
// 4 waves 2x2: each wave 64 rows x 128 cols per pass; acc = 4x8 f32x4.
// A: fp32 register-direct from xq + in-register split (no LDS, no barrier).
// B: register-direct from pre-split frag-order ws (coalesced lane*16 loads).
// K-loop has ZERO __syncthreads -> compiler pipelines loads with fine vmcnt.
#define BM 128
#define NRT 59        // ceil(7500/128)
#define NBLK 1180     // NRT*20
#define CSTRIDE 65

__global__ __launch_bounds__(256, 2) void dn4_kernel(const float* __restrict__ xq,
                                                     const float* __restrict__ ws_ro,
                                                     float* __restrict__ ws) {
    __shared__ float Cs[BM * CSTRIDE];

    // XCD-grouping swizzle: consecutive idx (same bw) land on the same XCD.
    int x = blockIdx.x & 7, jb = blockIdx.x >> 3;
    int idx = x * 148 + jb;
    if (idx >= NBLK) return;
    int bw = idx / NRT; int rt = idx % NRT;
    int w = bw % WAY;   int b  = bw / WAY;

    int tid  = threadIdx.x;
    int lane = tid & 63;
    int wave = tid >> 6;
    int wr = wave >> 1, wc = wave & 1;
    int lfree = lane & 15;
    int lq    = lane >> 4;

    // A fragment row setup: frag jj covers rows 64*wr + 16*jj + lfree
    const float* aptr[4];
    float qv[4];
    #pragma unroll
    for (int jj = 0; jj < 4; ++jj) {
        int grow = rt * BM + 64 * wr + 16 * jj + lfree;
        bool ok = grow < QROWS;
        aptr[jj] = xq + ((size_t)b * QROWS + (ok ? grow : 0)) * D + lq * 8;
        qv[jj]   = ok ? ws_ro[WS_QINV + b * QROWS + grow] : 0.f;
    }
    const char* bh_g = (const char*)ws_ro + WS_BH_BYTE;
    const char* bl_g = (const char*)ws_ro + WS_BL_BYTE;

    float t0 = -1e30f, t1 = -1e30f, t2 = -1e30f, t3 = -1e30f, t4 = -1e30f;

    #pragma unroll 1
    for (int mcp = 0; mcp < 2; ++mcp) {
        float4v acc[4][8];
        #pragma unroll
        for (int jj = 0; jj < 4; ++jj)
            #pragma unroll
            for (int ii = 0; ii < 8; ++ii) {
                acc[jj][ii][0]=0.f; acc[jj][ii][1]=0.f; acc[jj][ii][2]=0.f; acc[jj][ii][3]=0.f;
            }
        // B byte offsets for this pass: ii<4 -> chunk mcp*2, ii>=4 -> chunk mcp*2+1
        unsigned bo[8];
        #pragma unroll
        for (int ii = 0; ii < 8; ++ii) {
            int c   = mcp * 2 + (ii >> 2);
            int cf8 = c * 8 + 4 * wc + (ii & 3);
            bo[ii] = (unsigned)((bw * 32 + cf8) * 20) * 1024u + (unsigned)(lane * 16);
        }

        // ---- barrier-free K-loop ----
        #pragma unroll 2
        for (int kt = 0; kt < 20; ++kt) {
            short8 ahf[4], alf[4];
            #pragma unroll
            for (int jj = 0; jj < 4; ++jj) {
                const float* p = aptr[jj] + kt * 32;
                float4 a0 = *(const float4*)p;
                float4 a1 = *(const float4*)(p + 4);
                split8(a0, a1, qv[jj], ahf[jj], alf[jj]);
            }
            #pragma unroll
            for (int ii = 0; ii < 8; ++ii) {
                unsigned o = bo[ii] + (unsigned)(kt * 1024);
                short8 bh = *(const short8*)(bh_g + o);
                short8 bl = *(const short8*)(bl_g + o);
                #pragma unroll
                for (int jj = 0; jj < 4; ++jj) {
                    acc[jj][ii] = __builtin_amdgcn_mfma_f32_16x16x32_bf16(ahf[jj], bh, acc[jj][ii], 0, 0, 0);
                    acc[jj][ii] = __builtin_amdgcn_mfma_f32_16x16x32_bf16(ahf[jj], bl, acc[jj][ii], 0, 0, 0);
                    acc[jj][ii] = __builtin_amdgcn_mfma_f32_16x16x32_bf16(alf[jj], bh, acc[jj][ii], 0, 0, 0);
                }
            }
        }

        // ---- scan: 4 rounds of 64 cols (C/D layout: col=lane&15, row=lq*4+reg)
        #pragma unroll 1
        for (int r = 0; r < 4; ++r) {
            int cg = r >> 1, h = r & 1;
            if (wc == h) {
                #pragma unroll
                for (int iiL = 0; iiL < 4; ++iiL) {
                    int ii = cg * 4 + iiL;
                    #pragma unroll
                    for (int jj = 0; jj < 4; ++jj) {
                        int rbase = 64 * wr + 16 * jj + lq * 4;
                        #pragma unroll
                        for (int rr = 0; rr < 4; ++rr)
                            Cs[(rbase + rr) * CSTRIDE + 16 * iiL + lfree] = acc[jj][ii][rr];
                    }
                }
            }
            __syncthreads();
            int m0 = (mcp * 2 + cg) * 128 + h * 64;
            int validc = M - m0; if (validc > 64) validc = 64;
            if (tid < BM && rt * BM + tid < QROWS) {
                for (int c = 0; c < validc; ++c) {
                    float v = Cs[tid * CSTRIDE + c];
                    if (v > t4) {
                        t4 = v;
                        if (t4 > t3) { float tmp = t3; t3 = t4; t4 = tmp; }
                        if (t3 > t2) { float tmp = t2; t2 = t3; t3 = tmp; }
                        if (t2 > t1) { float tmp = t1; t1 = t2; t2 = tmp; }
                        if (t1 > t0) { float tmp = t0; t0 = t1; t1 = tmp; }
                    }
                }
            }
            __syncthreads();
        }
    }

    if (tid < BM) {
        int grow = rt * BM + tid;
        if (grow < QROWS) {
            int q = grow / HW;
            atomicAdd(&ws[WS_FEAT + (b * Q + q) * 10 + 5 + w],
                      (t0 + t1 + t2 + t3 + t4) * (1.f / M));
        }
    }
}

// ---------------- kernel 5: BatchNorm (training stats over q) + dilated conv ---
__global__ void bn_conv_kernel(const float* __restrict__ gamma, const float* __restrict__ beta,
                               const float* __restrict__ convw, const float* __restrict__ wsr,
                               float* __restrict__ out) {
    __shared__ float mu[10], rstd[10];
    int b = blockIdx.x;
    const float* feat = wsr + WS_FEAT + b * Q * 10;
    int t = threadIdx.x;
    if (t < 10) {
        float s = 0.f;
        for (int q = 0; q < Q; ++q) s += feat[q * 10 + t];
        float m = s / Q;
        float ss = 0.f;
        for (int q = 0; q < Q; ++q) { float d = feat[q * 10 + t] - m; ss += d * d; }
        mu[t] = m;
        rstd[t] = rsqrtf(ss / Q + 1e-5f);
    }
    __syncthreads();
    if (t < Q * WAY) {
        int q = t / WAY, j = t % WAY;
        float bn0 = (feat[q * 10 + j]     - mu[j])     * rstd[j]     * gamma[j]     + beta[j];
        float bn1 = (feat[q * 10 + 5 + j] - mu[5 + j]) * rstd[5 + j] * gamma[5 + j] + beta[5 + j];
        out[(b * Q + q) * WAY + j] = convw[0] * bn0 + convw[1] * bn1;
    }
}

extern "C" void kernel_launch(void* const* d_in, const int* in_sizes, int n_in,
                              void* d_out, int out_size, void* d_ws, size_t ws_size,
                              hipStream_t stream) {
    const float* xq    = (const float*)d_in[0];
    const float* xs    = (const float*)d_in[1];
    const float* gamma = (const float*)d_in[2];
    const float* beta  = (const float*)d_in[3];
    const float* convw = (const float*)d_in[4];
    float* ws  = (float*)d_ws;
    float* out = (float*)d_out;

    presplit_b<<<20 * 32, 256, 0, stream>>>(xs, ws);            // sinv + frag-order B
    norms_kernel<<<(NDQ + 3) / 4, 256, 0, stream>>>(xq, ws);    // qinv
    means_kernel<<<BB * Q + BB * WAY, 256, 0, stream>>>(xq, xs, ws);
    cos_kernel<<<(BB * Q * WAY + 3) / 4, 256, 0, stream>>>(ws);
    dn4_kernel<<<8 * 148, 256, 0, stream>>>(xq, ws, ws);
    bn_conv_kernel<<<BB, 384, 0, stream>>>(gamma, beta, convw, ws, out);
}